// Round 11
// baseline (168.538 us; speedup 1.0000x reference)
//
#include <hip/hip_runtime.h>

// GNN collapse: out = A^8 (x · w_in) + sum_l gamma_l A^{8-l} 1 + b_dec
// where A = D_in^-1/2 Adj D_out^-1/2 (scalar field propagation).
//
// Lessons: coop grid.sync 10x worse than small launches (R5). Device-scope
// atomic/scattered-store ops cost ~28 B HBM traffic each, rate ~30 Gops/s
// (R2/R4/R7/R10) -> minimize memory-side op COUNT. Static __shared__ charged
// grid-wide (R8). Owner-computes needs block-parallelism AND per-thread ILP
// (R9->R10). R11: CSR fill with ZERO global atomics — dst histogram per
// (range, slice) gives disjoint slot sub-ranges; LDS packed cursors assign
// slots; plain ushort stores, XCD-grouped by range (b % NR).

#define PAD 48     // max in-degree bound; 48 ushorts = 96 B row
#define RS  8192   // nodes per range; LDS = RS/2 packed words = 16 KB
#define RH  (RS / 2)
#define QS  8      // src-histogram edge slices
#define QF  16     // dst-histogram / fill edge slices

// ---- prep: src hist + dst hist + coefficient chain, one dispatch ----
// blocks [0, NR*QS): src hist (r = b%NR, q = b/NR)
// blocks [NR*QS, NR*(QS+QF)): dst hist
// last block: coeff chain. coef[0..8]=gamma, coef[16..47]=w_in
__global__ __launch_bounds__(256) void prep_hist_kernel(
        const int* __restrict__ src, const int* __restrict__ dst,
        const float* __restrict__ W_embed, const float* __restrict__ b_embed,
        const float* __restrict__ Ws, const float* __restrict__ bs,
        const float* __restrict__ W_dec, float* __restrict__ coef,
        unsigned* __restrict__ pu_src, unsigned* __restrict__ pu_dst,
        int NR, int N, int E) {
    __shared__ unsigned lds[RH];   // 16 KB
    int b = blockIdx.x;
    int nsrc = NR * QS;
    int nhist = nsrc + NR * QF;
    if (b < nhist) {
        bool is_src = b < nsrc;
        int bb = is_src ? b : b - nsrc;
        int r = bb % NR, q = bb / NR;
        int Q = is_src ? QS : QF;
        const int* __restrict__ arr = is_src ? src : dst;
        unsigned* __restrict__ pu = is_src ? pu_src : pu_dst;
        for (int i = threadIdx.x; i < RH; i += 256) lds[i] = 0;
        __syncthreads();
        int base = r * RS;
        int per = ((E + Q - 1) / Q + 3) & ~3;
        int e0 = q * per;
        int e1 = e0 + per; if (e1 > E) e1 = E;
        if (e0 < E) {
            const int4* p4 = (const int4*)(arr + e0);
            int m4 = (e1 - e0) >> 2;
            for (int i = threadIdx.x; i < m4; i += 256) {
                int4 v = p4[i];
                int t;
                t = v.x - base; if ((unsigned)t < (unsigned)RS) atomicAdd(&lds[t >> 1], 1u << ((t & 1) * 16));
                t = v.y - base; if ((unsigned)t < (unsigned)RS) atomicAdd(&lds[t >> 1], 1u << ((t & 1) * 16));
                t = v.z - base; if ((unsigned)t < (unsigned)RS) atomicAdd(&lds[t >> 1], 1u << ((t & 1) * 16));
                t = v.w - base; if ((unsigned)t < (unsigned)RS) atomicAdd(&lds[t >> 1], 1u << ((t & 1) * 16));
            }
            for (int e = e0 + (m4 << 2) + threadIdx.x; e < e1; e += 256) {
                int t = arr[e] - base;
                if ((unsigned)t < (unsigned)RS) atomicAdd(&lds[t >> 1], 1u << ((t & 1) * 16));
            }
        }
        __syncthreads();
        unsigned* outp = pu + (size_t)(q * NR + r) * RH;
        for (int i = threadIdx.x; i < RH; i += 256) outp[i] = lds[i];
    } else if (b == nhist) {
        __shared__ float shv[64];
        __shared__ float shg[9];
        int i = threadIdx.x;
        if (i < 64) shv[i] = W_dec[i];
        __syncthreads();
        for (int l = 7; l >= 0; --l) {
            float a = 0.f;
            if (i < 64) {
                float p = bs[l * 64 + i] * shv[i];
                for (int d = 32; d; d >>= 1) p += __shfl_xor(p, d);
                if (i == 0) shg[l + 1] = p;
                const float* Wrow = Ws + l * 4096 + i * 64;
                for (int j = 0; j < 64; ++j) a += Wrow[j] * shv[j];
            }
            __syncthreads();
            if (i < 64) shv[i] = a;
            __syncthreads();
        }
        if (i < 64) {
            float p = b_embed[i] * shv[i];
            for (int d = 32; d; d >>= 1) p += __shfl_xor(p, d);
            if (i == 0) shg[0] = p;
        }
        __syncthreads();
        if (i < 32) {
            float a = 0.f;
            const float* Wr = W_embed + i * 64;
            for (int j = 0; j < 64; ++j) a += Wr[j] * shv[j];
            coef[16 + i] = a;
        }
        if (i < 9) coef[i] = shg[i];
    }
}

// ---- fill: owner-computes, zero global atomics ----
// block b: r = b % NR (XCD grouping heuristic), q = b / NR.
// LDS cursor[j] = packed per-node slot base = sum over slices q'<q of
// pu_dst counts (disjoint sub-ranges across q-blocks). Slots assigned by
// LDS returning-atomic; csr written with plain ushort stores. Block q=QF-1
// ends with cursor = exact in-degree -> writes packed cnt_in.
__global__ __launch_bounds__(256) void fill_kernel(
        const int* __restrict__ src, const int* __restrict__ dst,
        const unsigned* __restrict__ pu_dst, unsigned* __restrict__ cnt_in,
        unsigned short* __restrict__ csr, int NR, int E) {
    __shared__ unsigned cur[RH];   // 16 KB packed cursors
    int b = blockIdx.x;
    int r = b % NR, q = b / NR;
    for (int j = threadIdx.x; j < RH; j += 256) {
        unsigned s = 0;
        for (int qq = 0; qq < q; ++qq) s += pu_dst[(size_t)(qq * NR + r) * RH + j];
        cur[j] = s;   // packed add safe: per-half counts << 2^16
    }
    __syncthreads();
    int base = r * RS;
    int per = ((E + QF - 1) / QF + 3) & ~3;
    int e0 = q * per;
    int e1 = e0 + per; if (e1 > E) e1 = E;
    if (e0 < E) {
        const int4* s4p = (const int4*)(src + e0);
        const int4* d4p = (const int4*)(dst + e0);
        int m4 = (e1 - e0) >> 2;
        for (int i = threadIdx.x; i < m4; i += 256) {
            int4 sv = s4p[i];
            int4 dv = d4p[i];
            int t, sh, p; unsigned old;
            t = dv.x - base;
            if ((unsigned)t < (unsigned)RS) {
                sh = (t & 1) * 16; old = atomicAdd(&cur[t >> 1], 1u << sh);
                p = (old >> sh) & 0xFFFF;
                if (p < PAD) csr[(size_t)(base + t) * PAD + p] = (unsigned short)sv.x;
            }
            t = dv.y - base;
            if ((unsigned)t < (unsigned)RS) {
                sh = (t & 1) * 16; old = atomicAdd(&cur[t >> 1], 1u << sh);
                p = (old >> sh) & 0xFFFF;
                if (p < PAD) csr[(size_t)(base + t) * PAD + p] = (unsigned short)sv.y;
            }
            t = dv.z - base;
            if ((unsigned)t < (unsigned)RS) {
                sh = (t & 1) * 16; old = atomicAdd(&cur[t >> 1], 1u << sh);
                p = (old >> sh) & 0xFFFF;
                if (p < PAD) csr[(size_t)(base + t) * PAD + p] = (unsigned short)sv.z;
            }
            t = dv.w - base;
            if ((unsigned)t < (unsigned)RS) {
                sh = (t & 1) * 16; old = atomicAdd(&cur[t >> 1], 1u << sh);
                p = (old >> sh) & 0xFFFF;
                if (p < PAD) csr[(size_t)(base + t) * PAD + p] = (unsigned short)sv.w;
            }
        }
        for (int e = e0 + (m4 << 2) + threadIdx.x; e < e1; e += 256) {
            int t = dst[e] - base;
            if ((unsigned)t < (unsigned)RS) {
                int sh = (t & 1) * 16;
                unsigned old = atomicAdd(&cur[t >> 1], 1u << sh);
                int p = (old >> sh) & 0xFFFF;
                if (p < PAD) csr[(size_t)(base + t) * PAD + p] = (unsigned short)src[e];
            }
        }
    }
    __syncthreads();
    if (q == QF - 1)
        for (int j = threadIdx.x; j < RH; j += 256) cnt_in[(size_t)r * RH + j] = cur[j];
}

// ---- z0 + inv precompute (deg_out = sum of QS packed partials) ----
__global__ __launch_bounds__(256) void z0_kernel(
        const float* __restrict__ x, const float* __restrict__ coef,
        const unsigned* __restrict__ pu_src, const unsigned* __restrict__ cnt_in,
        float* __restrict__ inv_out, float* __restrict__ inv_in,
        float* __restrict__ ts0, int NR, int N) {
    __shared__ float w[33];
    if (threadIdx.x < 32) w[threadIdx.x] = coef[16 + threadIdx.x];
    if (threadIdx.x == 32) w[32] = coef[0];
    __syncthreads();
    int n = blockIdx.x * 256 + threadIdx.x;
    if (n >= N) return;
    const float4* xr = (const float4*)(x + (size_t)n * 32);
    float acc = 0.f;
#pragma unroll
    for (int q = 0; q < 8; ++q) {
        float4 vv = xr[q];
        acc += vv.x * w[q * 4] + vv.y * w[q * 4 + 1] + vv.z * w[q * 4 + 2] + vv.w * w[q * 4 + 3];
    }
    int r = n >> 13, j = (n & (RS - 1)) >> 1, sh = (n & 1) * 16;
    int co = 0;
#pragma unroll
    for (int q = 0; q < QS; ++q)
        co += (pu_src[(size_t)(q * NR + r) * RH + j] >> sh) & 0xFFFF;
    if (co < 1) co = 1;
    int ci = (cnt_in[n >> 1] >> sh) & 0xFFFF;
    if (ci < 1) ci = 1;
    float io = rsqrtf((float)co);
    inv_out[n] = io;
    inv_in[n] = rsqrtf((float)ci);
    ts0[n] = io * (acc + w[32]);
}

// ---- 4-lane-per-node gather: each sub-lane does <=4 entries per 16-stripe ----
__device__ __forceinline__ float quad_gather(const unsigned short* __restrict__ row,
                                             const float* __restrict__ ta,
                                             int c, int sub) {
    float acc = 0.f;
#pragma unroll
    for (int t = 0; t < PAD / 16; ++t) {
        int eb = sub * 4 + 16 * t;
        if (eb < c) {
            uint2 v = *(const uint2*)(row + eb);   // 4 ushorts, 8B-aligned
            unsigned i0 = v.x & 0xFFFF, i1 = v.x >> 16;
            unsigned i2 = v.y & 0xFFFF, i3 = v.y >> 16;
            acc += ta[i0];
            if (eb + 1 < c) acc += ta[i1];
            if (eb + 2 < c) acc += ta[i2];
            if (eb + 3 < c) acc += ta[i3];
        }
    }
    return acc;
}

// ts_out[n] = inv_out[n] * (inv_in[n] * gather + coef[k]);  4 threads per node
__global__ __launch_bounds__(256) void prop_kernel(
        const float* __restrict__ ts_in, float* __restrict__ ts_out,
        const float* __restrict__ inv_out, const float* __restrict__ inv_in,
        const unsigned* __restrict__ cnt_in, const unsigned short* __restrict__ csr,
        const float* __restrict__ coef, int k, int N) {
    int tid = blockIdx.x * 256 + threadIdx.x;
    int n = tid >> 2, sub = tid & 3;
    if (n >= N) return;
    int c = (cnt_in[n >> 1] >> ((n & 1) * 16)) & 0xFFFF;
    if (c > PAD) c = PAD;
    float acc = quad_gather(csr + (size_t)n * PAD, ts_in, c, sub);
    acc += __shfl_xor(acc, 1);
    acc += __shfl_xor(acc, 2);
    if (sub == 0) ts_out[n] = inv_out[n] * (inv_in[n] * acc + coef[k]);
}

// out[n] = inv_in[n] * gather + coef[8] + b_dec;  4 threads per node
__global__ __launch_bounds__(256) void final_kernel(
        const float* __restrict__ ts_in, float* __restrict__ out,
        const float* __restrict__ inv_in, const unsigned* __restrict__ cnt_in,
        const unsigned short* __restrict__ csr, const float* __restrict__ coef,
        const float* __restrict__ b_dec, int N) {
    int tid = blockIdx.x * 256 + threadIdx.x;
    int n = tid >> 2, sub = tid & 3;
    if (n >= N) return;
    int c = (cnt_in[n >> 1] >> ((n & 1) * 16)) & 0xFFFF;
    if (c > PAD) c = PAD;
    float acc = quad_gather(csr + (size_t)n * PAD, ts_in, c, sub);
    acc += __shfl_xor(acc, 1);
    acc += __shfl_xor(acc, 2);
    if (sub == 0) out[n] = inv_in[n] * acc + coef[8] + b_dec[0];
}

// ---- int-id fallback (N > 65536): R7 structure, int CSR, atomic counters ----
__global__ __launch_bounds__(256) void prep_kernel_i(
        const float* __restrict__ W_embed, const float* __restrict__ b_embed,
        const float* __restrict__ Ws, const float* __restrict__ bs,
        const float* __restrict__ W_dec, float* __restrict__ coef,
        int* __restrict__ cnt, int NZ) {
    int g = blockIdx.x * 256 + threadIdx.x;
    for (int i = g; i < NZ; i += gridDim.x * 256) cnt[i] = 0;
    if (blockIdx.x == 0) {
        __shared__ float shv[64];
        __shared__ float shg[9];
        int i = threadIdx.x;
        if (i < 64) shv[i] = W_dec[i];
        __syncthreads();
        for (int l = 7; l >= 0; --l) {
            float a = 0.f;
            if (i < 64) {
                float p = bs[l * 64 + i] * shv[i];
                for (int d = 32; d; d >>= 1) p += __shfl_xor(p, d);
                if (i == 0) shg[l + 1] = p;
                const float* Wrow = Ws + l * 4096 + i * 64;
                for (int j = 0; j < 64; ++j) a += Wrow[j] * shv[j];
            }
            __syncthreads();
            if (i < 64) shv[i] = a;
            __syncthreads();
        }
        if (i < 64) {
            float p = b_embed[i] * shv[i];
            for (int d = 32; d; d >>= 1) p += __shfl_xor(p, d);
            if (i == 0) shg[0] = p;
        }
        __syncthreads();
        if (i < 32) {
            float a = 0.f;
            const float* Wr = W_embed + i * 64;
            for (int j = 0; j < 64; ++j) a += Wr[j] * shv[j];
            coef[16 + i] = a;
        }
        if (i < 9) coef[i] = shg[i];
    }
}

__global__ __launch_bounds__(256) void fill_kernel_i(
        const int* __restrict__ src, const int* __restrict__ dst,
        int* __restrict__ cnt_out, int* __restrict__ cursor,
        int* __restrict__ csr, int E) {
    int i = blockIdx.x * 256 + threadIdx.x;
    if (i >= E) return;
    int s = src[i], d = dst[i];
    atomicAdd(&cnt_out[s], 1);
    int p = atomicAdd(&cursor[d], 1);
    if (p < PAD) csr[(size_t)d * PAD + p] = s;
}

__global__ __launch_bounds__(256) void z0_kernel_i(
        const float* __restrict__ x, const float* __restrict__ coef,
        const int* __restrict__ cnt_out, const int* __restrict__ cursor,
        float* __restrict__ inv_out, float* __restrict__ inv_in,
        float* __restrict__ ts0, int N) {
    __shared__ float w[33];
    if (threadIdx.x < 32) w[threadIdx.x] = coef[16 + threadIdx.x];
    if (threadIdx.x == 32) w[32] = coef[0];
    __syncthreads();
    int n = blockIdx.x * 256 + threadIdx.x;
    if (n >= N) return;
    const float4* xr = (const float4*)(x + (size_t)n * 32);
    float acc = 0.f;
#pragma unroll
    for (int q = 0; q < 8; ++q) {
        float4 vv = xr[q];
        acc += vv.x * w[q * 4] + vv.y * w[q * 4 + 1] + vv.z * w[q * 4 + 2] + vv.w * w[q * 4 + 3];
    }
    int co = cnt_out[n]; if (co < 1) co = 1;
    int ci = cursor[n];  if (ci < 1) ci = 1;
    float io = rsqrtf((float)co);
    inv_out[n] = io;
    inv_in[n] = rsqrtf((float)ci);
    ts0[n] = io * (acc + w[32]);
}

__global__ __launch_bounds__(256) void prop_kernel_i(
        const float* __restrict__ ts_in, float* __restrict__ ts_out,
        const float* __restrict__ inv_out, const float* __restrict__ inv_in,
        const int* __restrict__ cursor, const int* __restrict__ csr,
        const float* __restrict__ coef, int k, int N) {
    int n = blockIdx.x * 256 + threadIdx.x;
    if (n >= N) return;
    int c = cursor[n]; if (c > PAD) c = PAD;
    const int* row = csr + (size_t)n * PAD;
    float acc = 0.f;
    for (int e = 0; e < c; ++e) acc += ts_in[row[e]];
    ts_out[n] = inv_out[n] * (inv_in[n] * acc + coef[k]);
}

__global__ __launch_bounds__(256) void final_kernel_i(
        const float* __restrict__ ts_in, float* __restrict__ out,
        const float* __restrict__ inv_in, const int* __restrict__ cursor,
        const int* __restrict__ csr, const float* __restrict__ coef,
        const float* __restrict__ b_dec, int N) {
    int n = blockIdx.x * 256 + threadIdx.x;
    if (n >= N) return;
    int c = cursor[n]; if (c > PAD) c = PAD;
    const int* row = csr + (size_t)n * PAD;
    float acc = 0.f;
    for (int e = 0; e < c; ++e) acc += ts_in[row[e]];
    out[n] = inv_in[n] * acc + coef[8] + b_dec[0];
}

extern "C" void kernel_launch(void* const* d_in, const int* in_sizes, int n_in,
                              void* d_out, int out_size, void* d_ws, size_t ws_size,
                              hipStream_t stream) {
    const float* x       = (const float*)d_in[0];
    const int*   src     = (const int*)d_in[1];
    const int*   dst     = (const int*)d_in[2];
    const float* W_embed = (const float*)d_in[3];
    const float* b_embed = (const float*)d_in[4];
    const float* Ws      = (const float*)d_in[5];
    const float* bs      = (const float*)d_in[6];
    const float* W_dec   = (const float*)d_in[7];
    const float* b_dec   = (const float*)d_in[8];
    float* out = (float*)d_out;
    int N = in_sizes[0] / 32;
    int E = in_sizes[1];

    int nbl  = (N + 255) / 256;
    int nbl4 = (4 * N + 255) / 256;
    int ebl  = (E + 255) / 256;
    char* w = (char*)d_ws;

    if (N <= 65536) {
        int NR = (N + RS - 1) / RS;   // <= 8
        size_t o = 0;
        unsigned* pu_src = (unsigned*)(w + o); o += (size_t)NR * QS * RH * 4;
        unsigned* pu_dst = (unsigned*)(w + o); o += (size_t)NR * QF * RH * 4;
        unsigned* cnt_in = (unsigned*)(w + o); o += (size_t)NR * RH * 4;
        o = (o + 255) & ~(size_t)255;
        float* inv_out = (float*)(w + o); o += (size_t)N * 4; o = (o + 255) & ~(size_t)255;
        float* inv_in  = (float*)(w + o); o += (size_t)N * 4; o = (o + 255) & ~(size_t)255;
        float* coef    = (float*)(w + o); o += 256;
        float* tsA     = (float*)(w + o); o += (size_t)N * 4; o = (o + 255) & ~(size_t)255;
        float* tsB     = (float*)(w + o); o += (size_t)N * 4; o = (o + 255) & ~(size_t)255;
        unsigned short* csr = (unsigned short*)(w + o);

        prep_hist_kernel<<<NR * (QS + QF) + 1, 256, 0, stream>>>(
            src, dst, W_embed, b_embed, Ws, bs, W_dec, coef, pu_src, pu_dst, NR, N, E);
        fill_kernel<<<NR * QF, 256, 0, stream>>>(src, dst, pu_dst, cnt_in, csr, NR, E);
        z0_kernel<<<nbl, 256, 0, stream>>>(x, coef, pu_src, cnt_in, inv_out, inv_in, tsA, NR, N);
        float* ta = tsA; float* tb = tsB;
        for (int k = 1; k <= 7; ++k) {
            prop_kernel<<<nbl4, 256, 0, stream>>>(ta, tb, inv_out, inv_in, cnt_in, csr, coef, k, N);
            float* tmp = ta; ta = tb; tb = tmp;
        }
        final_kernel<<<nbl4, 256, 0, stream>>>(ta, out, inv_in, cnt_in, csr, coef, b_dec, N);
    } else {
        size_t o = 0;
        int* cursor  = (int*)(w + o); o += (size_t)N * 4;
        int* cnt_out = (int*)(w + o); o += (size_t)N * 4;
        o = (o + 255) & ~(size_t)255;
        float* inv_out = (float*)(w + o); o += (size_t)N * 4; o = (o + 255) & ~(size_t)255;
        float* inv_in  = (float*)(w + o); o += (size_t)N * 4; o = (o + 255) & ~(size_t)255;
        float* coef    = (float*)(w + o); o += 256;
        float* tsA     = (float*)(w + o); o += (size_t)N * 4; o = (o + 255) & ~(size_t)255;
        float* tsB     = (float*)(w + o); o += (size_t)N * 4; o = (o + 255) & ~(size_t)255;
        int* csr = (int*)(w + o);

        prep_kernel_i<<<128, 256, 0, stream>>>(W_embed, b_embed, Ws, bs, W_dec, coef, cursor, 2 * N);
        fill_kernel_i<<<ebl, 256, 0, stream>>>(src, dst, cnt_out, cursor, csr, E);
        z0_kernel_i<<<nbl, 256, 0, stream>>>(x, coef, cnt_out, cursor, inv_out, inv_in, tsA, N);
        float* ta = tsA; float* tb = tsB;
        for (int k = 1; k <= 7; ++k) {
            prop_kernel_i<<<nbl, 256, 0, stream>>>(ta, tb, inv_out, inv_in, cursor, csr, coef, k, N);
            float* tmp = ta; ta = tb; tb = tmp;
        }
        final_kernel_i<<<nbl, 256, 0, stream>>>(ta, out, inv_in, cursor, csr, coef, b_dec, N);
    }
}